// Round 3
// baseline (774.124 us; speedup 1.0000x reference)
//
#include <hip/hip_runtime.h>

#define EPS 1e-5f

typedef __attribute__((ext_vector_type(8))) short short8;
typedef __attribute__((ext_vector_type(4))) float float4v;

__device__ __forceinline__ unsigned short f2bf(float x) {
  unsigned int u = __builtin_bit_cast(unsigned int, x);
  u += 0x7fffu + ((u >> 16) & 1u);   // RNE to bf16
  return (unsigned short)(u >> 16);
}
__device__ __forceinline__ float bf2f(unsigned short h) {
  unsigned int u = ((unsigned int)h) << 16;
  return __builtin_bit_cast(float, u);
}

// ---------------- Kernel 1: LayerNorm (+ zero `inner` for attnv atomics) ----------------
// one wave per row (b,n); 4 rows per 256-thread block; 4160 rows total
__global__ __launch_bounds__(256) void ln_kernel(
    const float* __restrict__ x, const float* __restrict__ gamma,
    const float* __restrict__ beta, float* __restrict__ xn,
    float* __restrict__ inner) {
  // zero 4 floats of inner per thread: 1040 blocks * 1024 = 1,064,960 floats exactly
  {
    const int zi = blockIdx.x * 1024 + threadIdx.x * 4;
    float4 z; z.x = 0.f; z.y = 0.f; z.z = 0.f; z.w = 0.f;
    *(float4*)(inner + zi) = z;
  }
  const int row = blockIdx.x * 4 + (threadIdx.x >> 6);
  const int lane = threadIdx.x & 63;
  const float2 v = ((const float2*)(x + (size_t)row * 128))[lane];
  float s = v.x + v.y;
#pragma unroll
  for (int off = 1; off < 64; off <<= 1) s += __shfl_xor(s, off);
  const float mu = s * (1.f / 128.f);
  const float dx = v.x - mu, dy = v.y - mu;
  float qv = dx * dx + dy * dy;
#pragma unroll
  for (int off = 1; off < 64; off <<= 1) qv += __shfl_xor(qv, off);
  const float rstd = 1.f / sqrtf(qv * (1.f / 128.f) + EPS);
  const float2 g = ((const float2*)gamma)[lane];
  const float2 be = ((const float2*)beta)[lane];
  float2 o;
  o.x = dx * rstd * g.x + be.x;
  o.y = dy * rstd * g.y + be.y;
  ((float2*)(xn + (size_t)row * 128))[lane] = o;
}

// ---------------- Kernel 2: qk = xn @ Wqk  [4160,128]x[128,512] ----------------
// grid (130, 8): 32-row x 64-col tiles, fp32
__global__ __launch_bounds__(256) void qk_kernel(
    const float* __restrict__ xn, const float* __restrict__ Wqk,
    float* __restrict__ qk) {
  __shared__ float xsx[32][130];
  __shared__ float wsx[128][68];
  const int t = threadIdx.x;
  const int r0 = blockIdx.x * 32, c0 = blockIdx.y * 64;
  for (int i = t; i < 32 * 32; i += 256) {
    int r = i >> 5, c = (i & 31) << 2;
    float4 v = *(const float4*)(xn + (size_t)(r0 + r) * 128 + c);
    float* dst = &xsx[r][c];
    dst[0] = v.x; dst[1] = v.y; dst[2] = v.z; dst[3] = v.w;
  }
  for (int i = t; i < 128 * 16; i += 256) {
    int k = i >> 4, c = (i & 15) << 2;
    *(float4*)&wsx[k][c] = *(const float4*)(Wqk + (size_t)k * 512 + c0 + c);
  }
  __syncthreads();
  const int rr = (t >> 4) * 2, cc = (t & 15) * 4;
  float acc[2][4] = {{0.f, 0.f, 0.f, 0.f}, {0.f, 0.f, 0.f, 0.f}};
  for (int k = 0; k < 128; k++) {
    float4 wv4 = *(const float4*)&wsx[k][cc];
    float x0 = xsx[rr][k], x1 = xsx[rr + 1][k];
    acc[0][0] += x0 * wv4.x; acc[0][1] += x0 * wv4.y;
    acc[0][2] += x0 * wv4.z; acc[0][3] += x0 * wv4.w;
    acc[1][0] += x1 * wv4.x; acc[1][1] += x1 * wv4.y;
    acc[1][2] += x1 * wv4.z; acc[1][3] += x1 * wv4.w;
  }
#pragma unroll
  for (int r = 0; r < 2; r++) {
    float4 o;
    o.x = acc[r][0]; o.y = acc[r][1]; o.z = acc[r][2]; o.w = acc[r][3];
    *(float4*)(qk + (size_t)(r0 + rr + r) * 512 + c0 + cc) = o;
  }
}

// ---------------- Kernel 3: dots + softmax ----------------
// grid 512 = (b,h); writes attn[b][h][n][m] fp32
__global__ __launch_bounds__(256) void softmax_kernel(
    const float* __restrict__ qk, float* __restrict__ attn) {
  const int b = blockIdx.x >> 3, h = blockIdx.x & 7;
  __shared__ float qs[65][33];
  __shared__ float ks[65][33];
  __shared__ float dotsS[65][66];
  __shared__ float rsum[65];
  const int t = threadIdx.x;
  for (int i = t; i < 65 * 32; i += 256) {
    int n = i >> 5, d = i & 31;
    size_t base = ((size_t)b * 65 + n) * 512 + h * 32 + d;
    qs[n][d] = qk[base];
    ks[n][d] = qk[base + 256];
  }
  __syncthreads();
  const float scale = 0.17677669529663687f;  // 1/sqrt(32)
  for (int i = t; i < 65 * 65; i += 256) {
    int n = i / 65, mm = i - n * 65;
    float s = 0.f;
#pragma unroll
    for (int d = 0; d < 32; d++) s += qs[n][d] * ks[mm][d];
    dotsS[n][mm] = s * scale;
  }
  __syncthreads();
  if (t < 65) {
    float mx = -1e30f;
    for (int mm = 0; mm < 65; mm++) mx = fmaxf(mx, dotsS[t][mm]);
    float sum = 0.f;
    for (int mm = 0; mm < 65; mm++) {
      float e = __expf(dotsS[t][mm] - mx);
      dotsS[t][mm] = e;
      sum += e;
    }
    rsum[t] = 1.f / sum;
  }
  __syncthreads();
  const size_t obase = ((size_t)b * 8 + h) * 65 * 65;
  for (int i = t; i < 65 * 65; i += 256) {
    int n = i / 65;
    attn[obase + i] = dotsS[n][i - n * 65] * rsum[n];
  }
}

// ---------------- Kernel 4: the big contraction, m-chunked ----------------
// inner[b,n,h*32+e] += sum_{m in chunk} attn[b,h,n,m] * sum_d xn[b,n,d]*Wv[n,m,d,h*32+e]
// grid (520, 4) = (n,h) x m-chunk; 4 waves; xn split hi/lo bf16 (A in regs),
// Wv bf16 (LDS dbuf). Chunking: 4x blocks -> 4 resident blocks/CU (LDS 37.7KB,
// VGPR<=128 via launch_bounds(256,4)) to hide HBM latency with TLP.
// Wv loads are non-temporal: 554MB streamed once; keep L2/L3 for xn/attn reuse.
__global__ __launch_bounds__(256, 4) void attnv_kernel(
    const float* __restrict__ xn, const float* __restrict__ attn,
    const float* __restrict__ Wv, float* __restrict__ inner) {
  __shared__ __align__(16) char sbuf[33280];  // xs[64][130] fp32  OR  wv[2][32][128] bf16
  __shared__ float attnL[17 * 65];            // attnL[mloc*65 + b], chunk-local
  float* xs = (float*)sbuf;
  unsigned short* wvb = (unsigned short*)sbuf;

  const int nq = blockIdx.x >> 3, h = blockIdx.x & 7;
  const int mc = blockIdx.y;
  const int ms = (mc == 0) ? 0 : (17 + (mc - 1) * 16);
  const int cnt = (mc == 0) ? 17 : 16;

  const int t = threadIdx.x, lane = t & 63, w = t >> 6;
  const int boff = w * 16;
  const int er = lane & 15, q = lane >> 4;

  // Wv staging coords: this thread loads column e (within head), rows d0..d0+15
  const int e = t & 31;
  const int d0 = (t >> 5) * 16;
  const int kc0 = d0 >> 3;
  const float* wbase = Wv + (size_t)nq * 65 * 32768 + (size_t)ms * 32768
                          + (size_t)h * 32 + e;

  // issue m=ms loads early
  float stg[16];
  {
    const float* p = wbase + (size_t)d0 * 256;
#pragma unroll
    for (int i = 0; i < 16; i++) stg[i] = __builtin_nontemporal_load(p + (size_t)i * 256);
  }

  // attn chunk -> attnL[mloc*65+b]
  for (int i = t; i < cnt * 64; i += 256) {
    int mloc = i >> 6, b = i & 63;
    attnL[mloc * 65 + b] =
        attn[(((size_t)b * 8 + h) * 65 + nq) * 65 + ms + mloc];
  }
  // xn rows -> xs (stride 130)
  for (int i = t; i < 64 * 32; i += 256) {
    int b = i >> 5, c = (i & 31) << 2;
    float4 v = *(const float4*)(xn + ((size_t)b * 65 + nq) * 128 + c);
    float* dst = xs + b * 130 + c;
    dst[0] = v.x; dst[1] = v.y; dst[2] = v.z; dst[3] = v.w;
  }
  __syncthreads();

  // A fragments (hi/lo split), held in registers across the whole m-loop
  short8 ah[4], al[4];
  {
    const int arow = boff + er;
#pragma unroll
    for (int s = 0; s < 4; s++) {
#pragma unroll
      for (int j = 0; j < 8; j++) {
        float xv = xs[arow * 130 + s * 32 + q * 8 + j];
        unsigned short hi = f2bf(xv);
        ah[s][j] = (short)hi;
        al[s][j] = (short)f2bf(xv - bf2f(hi));
      }
    }
  }
  __syncthreads();  // xs dead; sbuf becomes Wv double buffer

  // write m=ms into buffer 0 (chunk-XOR swizzle: elem (e,k) at col ((k>>3)^(e&15))*8 + (k&7))
  {
    short8 w0, w1;
#pragma unroll
    for (int j = 0; j < 8; j++) {
      w0[j] = (short)f2bf(stg[j]);
      w1[j] = (short)f2bf(stg[8 + j]);
    }
    *(short8*)&wvb[e * 128 + ((kc0 ^ (e & 15)) << 3)] = w0;
    *(short8*)&wvb[e * 128 + (((kc0 + 1) ^ (e & 15)) << 3)] = w1;
  }
  __syncthreads();

  float4v acc0 = {0.f, 0.f, 0.f, 0.f}, acc1 = {0.f, 0.f, 0.f, 0.f};

  for (int i = 0; i < cnt; i++) {
    const int cur = i & 1;
    // prefetch i+1 into VGPRs (stays in flight across the barrier)
    if (i + 1 < cnt) {
      const float* p = wbase + (size_t)(i + 1) * 32768 + (size_t)d0 * 256;
#pragma unroll
      for (int j = 0; j < 16; j++) stg[j] = __builtin_nontemporal_load(p + (size_t)j * 256);
    }
    // consume buffer `cur`
    const unsigned short* wb = wvb + cur * 4096;
    float4v P0 = {0.f, 0.f, 0.f, 0.f}, P1 = {0.f, 0.f, 0.f, 0.f};
    __builtin_amdgcn_s_setprio(1);
#pragma unroll
    for (int s = 0; s < 4; s++) {
      const int kc = 4 * s + q;
      short8 b0 = *(const short8*)&wb[er * 128 + ((kc ^ er) << 3)];
      short8 b1 = *(const short8*)&wb[(er + 16) * 128 + ((kc ^ er) << 3)];
      P0 = __builtin_amdgcn_mfma_f32_16x16x32_bf16(ah[s], b0, P0, 0, 0, 0);
      P1 = __builtin_amdgcn_mfma_f32_16x16x32_bf16(ah[s], b1, P1, 0, 0, 0);
      P0 = __builtin_amdgcn_mfma_f32_16x16x32_bf16(al[s], b0, P0, 0, 0, 0);
      P1 = __builtin_amdgcn_mfma_f32_16x16x32_bf16(al[s], b1, P1, 0, 0, 0);
    }
    __builtin_amdgcn_s_setprio(0);
    {
      const float* ap = attnL + i * 65 + boff + q * 4;
#pragma unroll
      for (int r = 0; r < 4; r++) {
        float av = ap[r];
        acc0[r] += av * P0[r];
        acc1[r] += av * P1[r];
      }
    }
    // convert + write i+1 into the other buffer
    if (i + 1 < cnt) {
      short8 w0, w1;
#pragma unroll
      for (int j = 0; j < 8; j++) {
        w0[j] = (short)f2bf(stg[j]);
        w1[j] = (short)f2bf(stg[8 + j]);
      }
      unsigned short* wbw = wvb + (1 - cur) * 4096;
      *(short8*)&wbw[e * 128 + ((kc0 ^ (e & 15)) << 3)] = w0;
      *(short8*)&wbw[e * 128 + (((kc0 + 1) ^ (e & 15)) << 3)] = w1;
    }
    __syncthreads();
  }

  // epilogue: D layout col=lane&15, row=(lane>>4)*4+r ; partial sum over m-chunk
#pragma unroll
  for (int r = 0; r < 4; r++) {
    int b = boff + q * 4 + r;
    size_t o = ((size_t)b * 65 + nq) * 256 + h * 32;
    atomicAdd(inner + o + er, acc0[r]);
    atomicAdd(inner + o + 16 + er, acc1[r]);
  }
}

// ---------------- Kernel 5: out = inner @ Wout + bout  [4160,256]x[256,128] ----------------
// grid 260: 16-row tiles, fp32
__global__ __launch_bounds__(256) void outproj_kernel(
    const float* __restrict__ inner, const float* __restrict__ Wout,
    const float* __restrict__ bout, float* __restrict__ out) {
  __shared__ float isx[16][258];
  __shared__ float wsx[64][132];
  const int t = threadIdx.x;
  const int r0 = blockIdx.x * 16;
  for (int i = t; i < 16 * 64; i += 256) {
    int r = i >> 6, c = (i & 63) << 2;
    float4 v = *(const float4*)(inner + (size_t)(r0 + r) * 256 + c);
    float* dst = &isx[r][c];
    dst[0] = v.x; dst[1] = v.y; dst[2] = v.z; dst[3] = v.w;
  }
  const int rr = (t >> 5) * 2, cc = (t & 31) * 4;
  float acc[2][4] = {{0.f, 0.f, 0.f, 0.f}, {0.f, 0.f, 0.f, 0.f}};
  for (int kc = 0; kc < 4; kc++) {
    __syncthreads();
    for (int i = t; i < 64 * 32; i += 256) {
      int k = i >> 5, c = (i & 31) << 2;
      *(float4*)&wsx[k][c] = *(const float4*)(Wout + (size_t)(kc * 64 + k) * 128 + c);
    }
    __syncthreads();
#pragma unroll 8
    for (int k = 0; k < 64; k++) {
      float4 wv4 = *(const float4*)&wsx[k][cc];
      float x0 = isx[rr][kc * 64 + k];
      float x1 = isx[rr + 1][kc * 64 + k];
      acc[0][0] += x0 * wv4.x; acc[0][1] += x0 * wv4.y;
      acc[0][2] += x0 * wv4.z; acc[0][3] += x0 * wv4.w;
      acc[1][0] += x1 * wv4.x; acc[1][1] += x1 * wv4.y;
      acc[1][2] += x1 * wv4.z; acc[1][3] += x1 * wv4.w;
    }
  }
  float4 bb = *(const float4*)(bout + cc);
#pragma unroll
  for (int r = 0; r < 2; r++) {
    float4 o;
    o.x = acc[r][0] + bb.x; o.y = acc[r][1] + bb.y;
    o.z = acc[r][2] + bb.z; o.w = acc[r][3] + bb.w;
    *(float4*)(out + (size_t)(r0 + rr + r) * 128 + cc) = o;
  }
}

extern "C" void kernel_launch(void* const* d_in, const int* in_sizes, int n_in,
                              void* d_out, int out_size, void* d_ws, size_t ws_size,
                              hipStream_t stream) {
  const float* x     = (const float*)d_in[0];
  const float* gamma = (const float*)d_in[1];
  const float* beta  = (const float*)d_in[2];
  const float* Wqk   = (const float*)d_in[3];
  const float* Wv    = (const float*)d_in[4];
  const float* Wout  = (const float*)d_in[5];
  const float* bout  = (const float*)d_in[6];
  float* out = (float*)d_out;
  float* ws  = (float*)d_ws;

  float* xn    = ws;                  // 532,480
  float* qk    = ws + 532480;         // 2,129,920
  float* attn  = ws + 2662400;        // 2,163,200
  float* inner = ws + 4825600;        // 1,064,960   (total 23.6 MB)

  ln_kernel<<<1040, 256, 0, stream>>>(x, gamma, beta, xn, inner);
  qk_kernel<<<dim3(130, 8), 256, 0, stream>>>(xn, Wqk, qk);
  softmax_kernel<<<512, 256, 0, stream>>>(qk, attn);
  attnv_kernel<<<dim3(520, 4), 256, 0, stream>>>(xn, attn, Wv, inner);
  outproj_kernel<<<260, 256, 0, stream>>>(inner, Wout, bout, out);
}

// Round 4
// 768.276 us; speedup vs baseline: 1.0076x; 1.0076x over previous
//
#include <hip/hip_runtime.h>

#define EPS 1e-5f

typedef __attribute__((ext_vector_type(8))) short short8;
typedef __attribute__((ext_vector_type(4))) float float4v;

__device__ __forceinline__ unsigned short f2bf(float x) {
  unsigned int u = __builtin_bit_cast(unsigned int, x);
  u += 0x7fffu + ((u >> 16) & 1u);   // RNE to bf16
  return (unsigned short)(u >> 16);
}
__device__ __forceinline__ float bf2f(unsigned short h) {
  unsigned int u = ((unsigned int)h) << 16;
  return __builtin_bit_cast(float, u);
}

// ---------------- Kernel 1: LayerNorm (+ zero `inner` for attnv atomics) ----------------
__global__ __launch_bounds__(256) void ln_kernel(
    const float* __restrict__ x, const float* __restrict__ gamma,
    const float* __restrict__ beta, float* __restrict__ xn,
    float* __restrict__ inner) {
  {
    const int zi = blockIdx.x * 1024 + threadIdx.x * 4;
    float4 z; z.x = 0.f; z.y = 0.f; z.z = 0.f; z.w = 0.f;
    *(float4*)(inner + zi) = z;
  }
  const int row = blockIdx.x * 4 + (threadIdx.x >> 6);
  const int lane = threadIdx.x & 63;
  const float2 v = ((const float2*)(x + (size_t)row * 128))[lane];
  float s = v.x + v.y;
#pragma unroll
  for (int off = 1; off < 64; off <<= 1) s += __shfl_xor(s, off);
  const float mu = s * (1.f / 128.f);
  const float dx = v.x - mu, dy = v.y - mu;
  float qv = dx * dx + dy * dy;
#pragma unroll
  for (int off = 1; off < 64; off <<= 1) qv += __shfl_xor(qv, off);
  const float rstd = 1.f / sqrtf(qv * (1.f / 128.f) + EPS);
  const float2 g = ((const float2*)gamma)[lane];
  const float2 be = ((const float2*)beta)[lane];
  float2 o;
  o.x = dx * rstd * g.x + be.x;
  o.y = dy * rstd * g.y + be.y;
  ((float2*)(xn + (size_t)row * 128))[lane] = o;
}

// ---------------- Kernel 2: qk = xn @ Wqk  [4160,128]x[128,512] ----------------
__global__ __launch_bounds__(256) void qk_kernel(
    const float* __restrict__ xn, const float* __restrict__ Wqk,
    float* __restrict__ qk) {
  __shared__ float xsx[32][130];
  __shared__ float wsx[128][68];
  const int t = threadIdx.x;
  const int r0 = blockIdx.x * 32, c0 = blockIdx.y * 64;
  for (int i = t; i < 32 * 32; i += 256) {
    int r = i >> 5, c = (i & 31) << 2;
    float4 v = *(const float4*)(xn + (size_t)(r0 + r) * 128 + c);
    float* dst = &xsx[r][c];
    dst[0] = v.x; dst[1] = v.y; dst[2] = v.z; dst[3] = v.w;
  }
  for (int i = t; i < 128 * 16; i += 256) {
    int k = i >> 4, c = (i & 15) << 2;
    *(float4*)&wsx[k][c] = *(const float4*)(Wqk + (size_t)k * 512 + c0 + c);
  }
  __syncthreads();
  const int rr = (t >> 4) * 2, cc = (t & 15) * 4;
  float acc[2][4] = {{0.f, 0.f, 0.f, 0.f}, {0.f, 0.f, 0.f, 0.f}};
  for (int k = 0; k < 128; k++) {
    float4 wv4 = *(const float4*)&wsx[k][cc];
    float x0 = xsx[rr][k], x1 = xsx[rr + 1][k];
    acc[0][0] += x0 * wv4.x; acc[0][1] += x0 * wv4.y;
    acc[0][2] += x0 * wv4.z; acc[0][3] += x0 * wv4.w;
    acc[1][0] += x1 * wv4.x; acc[1][1] += x1 * wv4.y;
    acc[1][2] += x1 * wv4.z; acc[1][3] += x1 * wv4.w;
  }
#pragma unroll
  for (int r = 0; r < 2; r++) {
    float4 o;
    o.x = acc[r][0]; o.y = acc[r][1]; o.z = acc[r][2]; o.w = acc[r][3];
    *(float4*)(qk + (size_t)(r0 + rr + r) * 512 + c0 + cc) = o;
  }
}

// ---------------- Kernel 3: dots + softmax ----------------
__global__ __launch_bounds__(256) void softmax_kernel(
    const float* __restrict__ qk, float* __restrict__ attn) {
  const int b = blockIdx.x >> 3, h = blockIdx.x & 7;
  __shared__ float qs[65][33];
  __shared__ float ks[65][33];
  __shared__ float dotsS[65][66];
  __shared__ float rsum[65];
  const int t = threadIdx.x;
  for (int i = t; i < 65 * 32; i += 256) {
    int n = i >> 5, d = i & 31;
    size_t base = ((size_t)b * 65 + n) * 512 + h * 32 + d;
    qs[n][d] = qk[base];
    ks[n][d] = qk[base + 256];
  }
  __syncthreads();
  const float scale = 0.17677669529663687f;  // 1/sqrt(32)
  for (int i = t; i < 65 * 65; i += 256) {
    int n = i / 65, mm = i - n * 65;
    float s = 0.f;
#pragma unroll
    for (int d = 0; d < 32; d++) s += qs[n][d] * ks[mm][d];
    dotsS[n][mm] = s * scale;
  }
  __syncthreads();
  if (t < 65) {
    float mx = -1e30f;
    for (int mm = 0; mm < 65; mm++) mx = fmaxf(mx, dotsS[t][mm]);
    float sum = 0.f;
    for (int mm = 0; mm < 65; mm++) {
      float e = __expf(dotsS[t][mm] - mx);
      dotsS[t][mm] = e;
      sum += e;
    }
    rsum[t] = 1.f / sum;
  }
  __syncthreads();
  const size_t obase = ((size_t)b * 8 + h) * 65 * 65;
  for (int i = t; i < 65 * 65; i += 256) {
    int n = i / 65;
    attn[obase + i] = dotsS[n][i - n * 65] * rsum[n];
  }
}

// ---------------- Kernel 4: the big contraction, m-chunked + depth-2 prefetch ----------------
// inner[b,n,h*32+e] += sum_{m in chunk} attn[b,h,n,m] * sum_d xn[b,n,d]*Wv[n,m,d,h*32+e]
// grid (520, 4) = (n,h) x m-chunk; 4 waves; xn split hi/lo bf16 (A in regs),
// Wv bf16 (LDS dbuf). Depth-2 register prefetch (stgA/stgB ping-pong): loads for
// m+2 issued at iter m, so the vmcnt wait before convert targets loads a full
// iteration (~1000cy) old -> stall ~0 regardless of cross-block phase locking.
__global__ __launch_bounds__(256, 4) void attnv_kernel(
    const float* __restrict__ xn, const float* __restrict__ attn,
    const float* __restrict__ Wv, float* __restrict__ inner) {
  __shared__ __align__(16) char sbuf[33280];  // xs[64][130] fp32  OR  wv[2][32][128] bf16
  __shared__ float attnL[17 * 65];            // attnL[mloc*65 + b], chunk-local
  float* xs = (float*)sbuf;
  unsigned short* wvb = (unsigned short*)sbuf;

  const int nq = blockIdx.x >> 3, h = blockIdx.x & 7;
  const int mc = blockIdx.y;
  const int ms = (mc == 0) ? 0 : (17 + (mc - 1) * 16);
  const int cnt = (mc == 0) ? 17 : 16;

  const int t = threadIdx.x, lane = t & 63, w = t >> 6;
  const int boff = w * 16;
  const int er = lane & 15, q = lane >> 4;

  const int e = t & 31;
  const int d0 = (t >> 5) * 16;
  const int kc0 = d0 >> 3;
  const float* wbase = Wv + (size_t)nq * 65 * 32768 + (size_t)ms * 32768
                          + (size_t)h * 32 + e;

#define ISSUE(dst, mm) do {                                                   \
    const float* p_ = wbase + (size_t)(mm) * 32768 + (size_t)d0 * 256;        \
    _Pragma("unroll")                                                         \
    for (int j_ = 0; j_ < 16; j_++)                                           \
      dst[j_] = __builtin_nontemporal_load(p_ + (size_t)j_ * 256);            \
  } while (0)

#define CONVWRITE(src, buf) do {                                              \
    short8 cw0_, cw1_;                                                        \
    _Pragma("unroll")                                                         \
    for (int j_ = 0; j_ < 8; j_++) {                                          \
      cw0_[j_] = (short)f2bf(src[j_]);                                        \
      cw1_[j_] = (short)f2bf(src[8 + j_]);                                    \
    }                                                                         \
    unsigned short* wbw_ = wvb + (buf) * 4096;                                \
    *(short8*)&wbw_[e * 128 + ((kc0 ^ (e & 15)) << 3)] = cw0_;                \
    *(short8*)&wbw_[e * 128 + (((kc0 + 1) ^ (e & 15)) << 3)] = cw1_;          \
  } while (0)

#define MFMA_BODY(buf, ii) do {                                               \
    const unsigned short* wb_ = wvb + (buf) * 4096;                           \
    float4v P0 = {0.f, 0.f, 0.f, 0.f}, P1 = {0.f, 0.f, 0.f, 0.f};             \
    __builtin_amdgcn_s_setprio(1);                                            \
    _Pragma("unroll")                                                         \
    for (int s_ = 0; s_ < 4; s_++) {                                          \
      const int kc_ = 4 * s_ + q;                                             \
      short8 b0_ = *(const short8*)&wb_[er * 128 + ((kc_ ^ er) << 3)];        \
      short8 b1_ = *(const short8*)&wb_[(er + 16) * 128 + ((kc_ ^ er) << 3)]; \
      P0 = __builtin_amdgcn_mfma_f32_16x16x32_bf16(ah[s_], b0_, P0, 0, 0, 0); \
      P1 = __builtin_amdgcn_mfma_f32_16x16x32_bf16(ah[s_], b1_, P1, 0, 0, 0); \
      P0 = __builtin_amdgcn_mfma_f32_16x16x32_bf16(al[s_], b0_, P0, 0, 0, 0); \
      P1 = __builtin_amdgcn_mfma_f32_16x16x32_bf16(al[s_], b1_, P1, 0, 0, 0); \
    }                                                                         \
    __builtin_amdgcn_s_setprio(0);                                            \
    const float* ap_ = attnL + (ii) * 65 + boff + q * 4;                      \
    _Pragma("unroll")                                                         \
    for (int r_ = 0; r_ < 4; r_++) {                                          \
      float av_ = ap_[r_];                                                    \
      acc0[r_] += av_ * P0[r_];                                               \
      acc1[r_] += av_ * P1[r_];                                               \
    }                                                                         \
  } while (0)

  // depth-2 prologue: issue m=0 and m=1 loads immediately
  float stgA[16], stgB[16];
  ISSUE(stgA, 0);
  ISSUE(stgB, 1);

  // attn chunk -> attnL[mloc*65+b]
  for (int i = t; i < cnt * 64; i += 256) {
    int mloc = i >> 6, b = i & 63;
    attnL[mloc * 65 + b] =
        attn[(((size_t)b * 8 + h) * 65 + nq) * 65 + ms + mloc];
  }
  // xn rows -> xs (stride 130)
  for (int i = t; i < 64 * 32; i += 256) {
    int b = i >> 5, c = (i & 31) << 2;
    float4 v = *(const float4*)(xn + ((size_t)b * 65 + nq) * 128 + c);
    float* dst = xs + b * 130 + c;
    dst[0] = v.x; dst[1] = v.y; dst[2] = v.z; dst[3] = v.w;
  }
  __syncthreads();

  // A fragments (hi/lo split), held in registers across the whole m-loop
  short8 ah[4], al[4];
  {
    const int arow = boff + er;
#pragma unroll
    for (int s = 0; s < 4; s++) {
#pragma unroll
      for (int j = 0; j < 8; j++) {
        float xv = xs[arow * 130 + s * 32 + q * 8 + j];
        unsigned short hi = f2bf(xv);
        ah[s][j] = (short)hi;
        al[s][j] = (short)f2bf(xv - bf2f(hi));
      }
    }
  }
  __syncthreads();  // xs dead; sbuf becomes Wv double buffer

  // write m=0 into buffer 0 (waits only stgA's 16 loads; stgB stays in flight)
  CONVWRITE(stgA, 0);
  __syncthreads();

  float4v acc0 = {0.f, 0.f, 0.f, 0.f}, acc1 = {0.f, 0.f, 0.f, 0.f};

  // main loop, hand-unrolled x2 so stgA/stgB indexing is static (no scratch)
  for (int i = 0; i < cnt; i += 2) {
    // even body: consume buf0 (m=i); stgB holds loads(i+1); issue loads(i+2)->stgA
    if (i + 2 < cnt) ISSUE(stgA, i + 2);
    MFMA_BODY(0, i);
    if (i + 1 < cnt) CONVWRITE(stgB, 1);
    __syncthreads();
    if (i + 1 < cnt) {
      // odd body: consume buf1 (m=i+1); stgA holds loads(i+2); issue loads(i+3)->stgB
      if (i + 3 < cnt) ISSUE(stgB, i + 3);
      MFMA_BODY(1, i + 1);
      if (i + 2 < cnt) CONVWRITE(stgA, 0);
      __syncthreads();
    }
  }

#undef ISSUE
#undef CONVWRITE
#undef MFMA_BODY

  // epilogue: D layout col=lane&15, row=(lane>>4)*4+r ; partial sum over m-chunk
#pragma unroll
  for (int r = 0; r < 4; r++) {
    int b = boff + q * 4 + r;
    size_t o = ((size_t)b * 65 + nq) * 256 + h * 32;
    atomicAdd(inner + o + er, acc0[r]);
    atomicAdd(inner + o + 16 + er, acc1[r]);
  }
}

// ---------------- Kernel 5: out = inner @ Wout + bout  [4160,256]x[256,128] ----------------
__global__ __launch_bounds__(256) void outproj_kernel(
    const float* __restrict__ inner, const float* __restrict__ Wout,
    const float* __restrict__ bout, float* __restrict__ out) {
  __shared__ float isx[16][258];
  __shared__ float wsx[64][132];
  const int t = threadIdx.x;
  const int r0 = blockIdx.x * 16;
  for (int i = t; i < 16 * 64; i += 256) {
    int r = i >> 6, c = (i & 63) << 2;
    float4 v = *(const float4*)(inner + (size_t)(r0 + r) * 256 + c);
    float* dst = &isx[r][c];
    dst[0] = v.x; dst[1] = v.y; dst[2] = v.z; dst[3] = v.w;
  }
  const int rr = (t >> 5) * 2, cc = (t & 31) * 4;
  float acc[2][4] = {{0.f, 0.f, 0.f, 0.f}, {0.f, 0.f, 0.f, 0.f}};
  for (int kc = 0; kc < 4; kc++) {
    __syncthreads();
    for (int i = t; i < 64 * 32; i += 256) {
      int k = i >> 5, c = (i & 31) << 2;
      *(float4*)&wsx[k][c] = *(const float4*)(Wout + (size_t)(kc * 64 + k) * 128 + c);
    }
    __syncthreads();
#pragma unroll 8
    for (int k = 0; k < 64; k++) {
      float4 wv4 = *(const float4*)&wsx[k][cc];
      float x0 = isx[rr][kc * 64 + k];
      float x1 = isx[rr + 1][kc * 64 + k];
      acc[0][0] += x0 * wv4.x; acc[0][1] += x0 * wv4.y;
      acc[0][2] += x0 * wv4.z; acc[0][3] += x0 * wv4.w;
      acc[1][0] += x1 * wv4.x; acc[1][1] += x1 * wv4.y;
      acc[1][2] += x1 * wv4.z; acc[1][3] += x1 * wv4.w;
    }
  }
  float4 bb = *(const float4*)(bout + cc);
#pragma unroll
  for (int r = 0; r < 2; r++) {
    float4 o;
    o.x = acc[r][0] + bb.x; o.y = acc[r][1] + bb.y;
    o.z = acc[r][2] + bb.z; o.w = acc[r][3] + bb.w;
    *(float4*)(out + (size_t)(r0 + rr + r) * 128 + cc) = o;
  }
}

extern "C" void kernel_launch(void* const* d_in, const int* in_sizes, int n_in,
                              void* d_out, int out_size, void* d_ws, size_t ws_size,
                              hipStream_t stream) {
  const float* x     = (const float*)d_in[0];
  const float* gamma = (const float*)d_in[1];
  const float* beta  = (const float*)d_in[2];
  const float* Wqk   = (const float*)d_in[3];
  const float* Wv    = (const float*)d_in[4];
  const float* Wout  = (const float*)d_in[5];
  const float* bout  = (const float*)d_in[6];
  float* out = (float*)d_out;
  float* ws  = (float*)d_ws;

  float* xn    = ws;                  // 532,480
  float* qk    = ws + 532480;         // 2,129,920
  float* attn  = ws + 2662400;        // 2,163,200
  float* inner = ws + 4825600;        // 1,064,960   (total 23.6 MB)

  ln_kernel<<<1040, 256, 0, stream>>>(x, gamma, beta, xn, inner);
  qk_kernel<<<dim3(130, 8), 256, 0, stream>>>(xn, Wqk, qk);
  softmax_kernel<<<512, 256, 0, stream>>>(qk, attn);
  attnv_kernel<<<dim3(520, 4), 256, 0, stream>>>(xn, attn, Wv, inner);
  outproj_kernel<<<260, 256, 0, stream>>>(inner, Wout, bout, out);
}